// Round 2
// baseline (236.748 us; speedup 1.0000x reference)
//
#include <hip/hip_runtime.h>

// CANet fused kernel, round 7 == round 6 resubmitted (container infra failure,
// no signal obtained; source re-audited for hangs/OOB/races — none found).
// vs r5 (bench 224 us; main dispatch 139 us, MfmaUtil 17, VALU 42, conflicts 12.6M):
//  - prep_emb kernel FUSED into canet_main: each block converts its weight
//    fragments from global fp32 (L2-hot, one-time), loads bias float4s direct,
//    wave 0 computes the time embedding inline (same reduction order).
//    Removes the second launch + inter-kernel serialization (~85 us of
//    non-main-kernel time in the bench).
//  - wp_s bank-skew: old layout had q=0/2 and q=1/3 lane groups reading the
//    same 4-bank window (144 dwords == 16 mod 32) -> every conv weight f32x4
//    read was a 2-way b128 conflict (~12.3M cycles, matching the counter).
//    New layout adds +4*q dwords so the four q-groups hit disjoint quadrants.
//  - percS K-pad (cols 48..63) zeroed once pre-loop, per-iter pad write gone.

#define ACT_S 136     // 272 B rows (16B-aligned) for h1/h2 [px][ch]
#define PERC_S 72     // 144 B rows for perc [px][ch48->64]
#define NOISE_BASE 9437184   // 16*9*65536

typedef short bf16x8 __attribute__((ext_vector_type(8)));
typedef float f32x4 __attribute__((ext_vector_type(4)));

__device__ __forceinline__ short f2bf(float f) {
    union { float f; unsigned u; } cv; cv.f = f;
    unsigned r = cv.u + 0x7FFFu + ((cv.u >> 16) & 1u);
    return (short)(r >> 16);
}
// pack two fp32 -> dword of two bf16 (round-half-up): lo16=bf(f0), hi16=bf(f1)
__device__ __forceinline__ unsigned pk2bf(float f0, float f1) {
    union { float f; unsigned u; } a, b; a.f = f0; b.f = f1;
    return __builtin_amdgcn_perm(b.u + 0x8000u, a.u + 0x8000u, 0x07060302u);
}
// load 8 consecutive fp32 (16B-aligned) -> bf16x8
__device__ __forceinline__ bf16x8 cvt8(const float* __restrict__ p) {
    f32x4 a = *(const f32x4*)p;
    f32x4 b = *(const f32x4*)(p + 4);
    union { unsigned u[4]; bf16x8 v; } r;
    r.u[0] = pk2bf(a[0], a[1]);
    r.u[1] = pk2bf(a[2], a[3]);
    r.u[2] = pk2bf(b[0], b[1]);
    r.u[3] = pk2bf(b[2], b[3]);
    return r.v;
}

// ---------------- single fused kernel ----------------
// MFMA 16x16x32 (m89): A lane(i=lane&15,q) holds A[i][q*8+j]; B symmetric:
// lane holds B[q*8+j][i]. D: col(N)=lane&15, row(M)=q*4+r.
__global__ __launch_bounds__(256, 3) void canet_main(
    const float* __restrict__ xg,   // (16,3,256,256)
    const float* __restrict__ hg,   // (16,9,256,256)
    const int*   __restrict__ tG,
    const float* __restrict__ wpg,  // (48,1,3,3)
    const float* __restrict__ bpg,  // (48)
    const float* __restrict__ w1g,  // (128,48)
    const float* __restrict__ b1g,  // (128)
    const float* __restrict__ w2g,  // (128,128)
    const float* __restrict__ b2g,  // (128)
    const float* __restrict__ w3g,  // (12,128)
    const float* __restrict__ wtg,  // (3,256)
    const float* __restrict__ btg,  // (3)
    float* __restrict__ outg)
{
    __shared__ __align__(16) short percS[64 * PERC_S];
    __shared__ __align__(16) short h1S[64 * ACT_S];
    __shared__ __align__(16) short h2S[64 * ACT_S];
    __shared__ __align__(16) float wp_s[592];   // skewed: oc*12 + 4*(oc/12) + k
    __shared__ float bp_s[48];
    __shared__ float embS[4];

    const int tid = threadIdx.x;
    const int b = blockIdx.x >> 8;
    const int y = blockIdx.x & 255;

    // ---- stage conv weights (bank-skewed) + bias ----
    for (int i = tid; i < 576; i += 256) {
        int oc = i / 12, k = i % 12;
        wp_s[i + (oc / 12) * 4] = (k < 9) ? wpg[oc * 9 + k] : 0.0f;
    }
    if (tid < 48) bp_s[tid] = bpg[tid];

    // ---- zero percS K-pad (cols 48..63) once; never written again ----
    {
        int r = tid >> 2, c = tid & 3;
        *(uint2*)(percS + r * PERC_S + 48 + c * 4) = uint2{0u, 0u};
    }

    // ---- time embedding for this batch (wave 0 only) ----
    if (tid < 64) {
        const float LOG1E4 = 9.210340371976184f;
        float tv = (float)tG[b];
        float s0 = 0.f, s1 = 0.f, s2 = 0.f;
        #pragma unroll
        for (int ii = 0; ii < 2; ++ii) {
            int i = tid + ii * 64;
            float invf = __expf(-LOG1E4 * (float)i * (1.0f / 128.0f));
            float ang = tv * invf;
            float sn = sinf(ang), cs = cosf(ang);
            float ss = sn / (1.0f + __expf(-sn));
            float sc = cs / (1.0f + __expf(-cs));
            s0 += ss * wtg[0 * 256 + i] + sc * wtg[0 * 256 + i + 128];
            s1 += ss * wtg[1 * 256 + i] + sc * wtg[1 * 256 + i + 128];
            s2 += ss * wtg[2 * 256 + i] + sc * wtg[2 * 256 + i + 128];
        }
        #pragma unroll
        for (int off = 32; off; off >>= 1) {
            s0 += __shfl_down(s0, off);
            s1 += __shfl_down(s1, off);
            s2 += __shfl_down(s2, off);
        }
        if (tid == 0) {
            embS[0] = s0 + btg[0];
            embS[1] = s1 + btg[1];
            embS[2] = s2 + btg[2];
        }
    }

    const int wv = tid >> 6;
    const int lane = tid & 63;
    const int m = lane & 15;
    const int q = lane >> 4;

    // ---- weight fragments: convert from global fp32 (once per block) ----
    bf16x8 w1f[2][2], w2f[2][4], w3f[4];
    const bf16x8 zfrag = 0;
    #pragma unroll
    for (int j = 0; j < 2; ++j) {
        int n = wv * 32 + j * 16 + m;
        // w1 row has 48 cols; ks=1 needs cols 32+q*8 (pad zero for q>=2)
        w1f[j][0] = cvt8(w1g + n * 48 + q * 8);
        w1f[j][1] = (q < 2) ? cvt8(w1g + n * 48 + 32 + q * 8) : zfrag;
        #pragma unroll
        for (int ks = 0; ks < 4; ++ks)
            w2f[j][ks] = cvt8(w2g + n * 128 + ks * 32 + q * 8);
    }
    #pragma unroll
    for (int ks = 0; ks < 4; ++ks)
        w3f[ks] = (m < 12) ? cvt8(w3g + m * 128 + ks * 32 + q * 8) : zfrag;

    // bias vectors: D rows = channels (wv*32 + j*16 + q*4 + r)
    f32x4 b1v[2], b2v[2];
    #pragma unroll
    for (int j = 0; j < 2; ++j) {
        b1v[j] = *(const f32x4*)(b1g + wv * 32 + j * 16 + q * 4);
        b2v[j] = *(const f32x4*)(b2g + wv * 32 + j * 16 + q * 4);
    }

    // conv source pointers (lane's 3 input channels: ic = 3q + i3)
    const float* src3[3];
    #pragma unroll
    for (int i3 = 0; i3 < 3; ++i3) {
        int ic = 3 * q + i3;
        src3[i3] = (ic < 3) ? (xg + (((size_t)b * 3 + ic) << 16))
                            : (hg + (((size_t)b * 9 + (ic - 3)) << 16));
    }

    __syncthreads();   // wp_s/bp_s/embS/percS-pad ready

    const float embv = (m < 3) ? embS[m] : 0.0f;

    for (int it = 0; it < 4; ++it) {
        const int x0 = it * 64;
        const int px = x0 + wv * 16 + m;

        // ---- depthwise 3x3 conv -> percS[px][ch] ----
        {
            const int xm1 = px - (px > 0);
            const int xp1 = px + (px < 255);
            const bool okl = (px > 0), okr = (px < 255);
            short* prow = percS + (wv * 16 + m) * PERC_S;
            const bool interior = (y >= 1) && (y <= 254);
            #pragma unroll
            for (int i3 = 0; i3 < 3; ++i3) {
                const float* s = src3[i3];
                float tap[9];
                if (interior) {
                    #pragma unroll
                    for (int ky = 0; ky < 3; ++ky) {
                        const float* rp = s + (y + ky - 1) * 256;
                        float c0 = rp[xm1], c1 = rp[px], c2 = rp[xp1];
                        tap[ky * 3 + 0] = okl ? c0 : 0.0f;
                        tap[ky * 3 + 1] = c1;
                        tap[ky * 3 + 2] = okr ? c2 : 0.0f;
                    }
                } else {
                    #pragma unroll
                    for (int ky = 0; ky < 3; ++ky) {
                        int yy = y + ky - 1;
                        bool yok = (yy >= 0) && (yy < 256);
                        const float* rp = s + (yok ? yy : y) * 256;
                        float c0 = rp[xm1], c1 = rp[px], c2 = rp[xp1];
                        tap[ky * 3 + 0] = (yok && okl) ? c0 : 0.0f;
                        tap[ky * 3 + 1] = yok ? c1 : 0.0f;
                        tap[ky * 3 + 2] = (yok && okr) ? c2 : 0.0f;
                    }
                }
                float v[4];
                #pragma unroll
                for (int r = 0; r < 4; ++r) {
                    int oc = 12 * q + 4 * i3 + r;
                    const float* wrow = &wp_s[oc * 12 + 4 * q];   // bank-skewed
                    f32x4 w0 = *(const f32x4*)wrow;
                    f32x4 w1_ = *(const f32x4*)(wrow + 4);
                    float a = bp_s[oc];
                    a += w0[0] * tap[0] + w0[1] * tap[1] + w0[2] * tap[2] + w0[3] * tap[3];
                    a += w1_[0] * tap[4] + w1_[1] * tap[5] + w1_[2] * tap[6] + w1_[3] * tap[7];
                    a += wrow[8] * tap[8];
                    v[r] = a;
                }
                uint2 pk;
                pk.x = pk2bf(v[0], v[1]);
                pk.y = pk2bf(v[2], v[3]);
                *(uint2*)(prow + 12 * q + 4 * i3) = pk;
            }
            // K pad 48..63 stays zero (written once pre-loop)
        }
        __syncthreads();

        // ---- GEMM1 (swapped): D[ch][px] = w1 . perc^T ; write h1S[px][ch] ----
        #pragma unroll
        for (int nt = 0; nt < 4; ++nt) {
            f32x4 c0 = b1v[0], c1 = b1v[1];
            #pragma unroll
            for (int ks = 0; ks < 2; ++ks) {
                bf16x8 p = *(const bf16x8*)(percS + (nt * 16 + m) * PERC_S + ks * 32 + q * 8);
                c0 = __builtin_amdgcn_mfma_f32_16x16x32_bf16(w1f[0][ks], p, c0, 0, 0, 0);
                c1 = __builtin_amdgcn_mfma_f32_16x16x32_bf16(w1f[1][ks], p, c1, 0, 0, 0);
            }
            short* drow = h1S + (nt * 16 + m) * ACT_S + wv * 32 + q * 4;
            uint2 pk;
            pk.x = pk2bf(fmaxf(c0[0], 0.f), fmaxf(c0[1], 0.f));
            pk.y = pk2bf(fmaxf(c0[2], 0.f), fmaxf(c0[3], 0.f));
            *(uint2*)drow = pk;
            pk.x = pk2bf(fmaxf(c1[0], 0.f), fmaxf(c1[1], 0.f));
            pk.y = pk2bf(fmaxf(c1[2], 0.f), fmaxf(c1[3], 0.f));
            *(uint2*)(drow + 16) = pk;
        }
        __syncthreads();

        // ---- GEMM2 (swapped): D[ch][px] = w2 . h1^T ; write h2S[px][ch] ----
        #pragma unroll
        for (int nt = 0; nt < 4; ++nt) {
            f32x4 c0 = b2v[0], c1 = b2v[1];
            #pragma unroll
            for (int ks = 0; ks < 4; ++ks) {
                bf16x8 a = *(const bf16x8*)(h1S + (nt * 16 + m) * ACT_S + ks * 32 + q * 8);
                c0 = __builtin_amdgcn_mfma_f32_16x16x32_bf16(w2f[0][ks], a, c0, 0, 0, 0);
                c1 = __builtin_amdgcn_mfma_f32_16x16x32_bf16(w2f[1][ks], a, c1, 0, 0, 0);
            }
            short* drow = h2S + (nt * 16 + m) * ACT_S + wv * 32 + q * 4;
            uint2 pk;
            pk.x = pk2bf(fmaxf(c0[0], 0.f), fmaxf(c0[1], 0.f));
            pk.y = pk2bf(fmaxf(c0[2], 0.f), fmaxf(c0[3], 0.f));
            *(uint2*)drow = pk;
            pk.x = pk2bf(fmaxf(c1[0], 0.f), fmaxf(c1[1], 0.f));
            pk.y = pk2bf(fmaxf(c1[2], 0.f), fmaxf(c1[3], 0.f));
            *(uint2*)(drow + 16) = pk;
        }
        __syncthreads();

        // ---- GEMM3: out = h2 . w3^T ; D col=oc, row=px; float4 store ----
        {
            f32x4 acc = {0.f, 0.f, 0.f, 0.f};
            #pragma unroll
            for (int ks = 0; ks < 4; ++ks) {
                bf16x8 a = *(const bf16x8*)(h2S + (wv * 16 + m) * ACT_S + ks * 32 + q * 8);
                acc = __builtin_amdgcn_mfma_f32_16x16x32_bf16(a, w3f[ks], acc, 0, 0, 0);
            }
            if (m < 12) {
                int xx0 = x0 + wv * 16 + q * 4;
                size_t idx;
                if (m < 3) {
                    idx = (size_t)NOISE_BASE + (((size_t)b * 3 + m) << 16) + (size_t)y * 256 + xx0;
                } else {
                    idx = (((size_t)b * 9 + (m - 3)) << 16) + (size_t)y * 256 + xx0;
                }
                f32x4 vst = {acc[0] + embv, acc[1] + embv, acc[2] + embv, acc[3] + embv};
                *(f32x4*)(outg + idx) = vst;
            }
        }
        // next-iter conv writes percS only after this iter's GEMM1 barrier.
    }
}

extern "C" void kernel_launch(void* const* d_in, const int* in_sizes, int n_in,
                              void* d_out, int out_size, void* d_ws, size_t ws_size,
                              hipStream_t stream) {
    const float* xg  = (const float*)d_in[0];
    const float* hg  = (const float*)d_in[1];
    const int*   tg  = (const int*)  d_in[2];
    const float* wpg = (const float*)d_in[3];
    const float* bpg = (const float*)d_in[4];
    const float* w1g = (const float*)d_in[5];
    const float* b1g = (const float*)d_in[6];
    const float* w2g = (const float*)d_in[7];
    const float* b2g = (const float*)d_in[8];
    const float* w3g = (const float*)d_in[9];
    const float* wtg = (const float*)d_in[10];
    const float* btg = (const float*)d_in[11];
    float* outg = (float*)d_out;
    (void)d_ws; (void)ws_size;

    canet_main<<<4096, 256, 0, stream>>>(xg, hg, tg, wpg, bpg, w1g, b1g, w2g,
                                         b2g, w3g, wtg, btg, outg);
}

// Round 3
// 235.929 us; speedup vs baseline: 1.0035x; 1.0035x over previous
//
#include <hip/hip_runtime.h>

// CANet fused kernel, round 8.
// Post-mortem r6: (a) prep-fusion REVERTED — per-block weight-convert prologue
//   cost ~15us main vs ~5us bench savings (main 139->157). Back to two kernels
//   with bf16 weights staged in workspace (r5 structure, proven 139us).
// (b) wp_s skew did NOT move SQ_LDS_BANK_CONFLICT (12.58M->12.39M): conflicts
//   are in the activation-tile LDS traffic (1.8M ds_read_b128 at 272B row
//   stride ~= 7 extra cyc each). Fix per T2/G4: rows -> 256B (ACT_S 128,
//   PERC_S 64) + XOR swizzle col ^= ((row&7)<<3) [shorts] on ALL reads+writes.
//   All rows a lane touches are == m (mod 16), so one rsw = (m&7)<<3 serves
//   every site; XOR touches short-bits 3..5 so 4-short writes / 8-short reads
//   keep alignment and round-trip consistently.
// (c) percS K-pad (cols 48..63) zeroed once pre-loop (swizzled), per-iter pad
//   write removed.

#define ACT_S 128     // 256 B rows for h1/h2 [px][ch], XOR-swizzled
#define PERC_S 64     // 128 B rows for perc [px][ch48->64], XOR-swizzled
#define NOISE_BASE 9437184   // 16*9*65536

// d_ws: shorts [0,26624): w1b[128][64]@0, w2b[128][128]@8192, w3b[16][128]@24576
// floats @ WSF_OFF: bp[48], b1[128], b2[128], wp[432], emb[48]
#define WSF_OFF 13312
#define WSF_BP 0
#define WSF_B1 48
#define WSF_B2 176
#define WSF_WP 304
#define WSF_EMB 736

typedef short bf16x8 __attribute__((ext_vector_type(8)));
typedef float f32x4 __attribute__((ext_vector_type(4)));

__device__ __forceinline__ short f2bf(float f) {
    union { float f; unsigned u; } cv; cv.f = f;
    unsigned r = cv.u + 0x7FFFu + ((cv.u >> 16) & 1u);
    return (short)(r >> 16);
}
// pack two fp32 -> dword of two bf16 (round-half-up): lo16=bf(f0), hi16=bf(f1)
__device__ __forceinline__ unsigned pk2bf(float f0, float f1) {
    union { float f; unsigned u; } a, b; a.f = f0; b.f = f1;
    return __builtin_amdgcn_perm(b.u + 0x8000u, a.u + 0x8000u, 0x07060302u);
}

// ---------------- weight prep + time embedding (one launch) ----------------
__global__ void prep_emb_kernel(const float* __restrict__ wpg, const float* __restrict__ bpg,
                                const float* __restrict__ w1g, const float* __restrict__ b1g,
                                const float* __restrict__ w2g, const float* __restrict__ b2g,
                                const float* __restrict__ w3g,
                                const int* __restrict__ t,
                                const float* __restrict__ wt, const float* __restrict__ bt,
                                short* __restrict__ wsb, float* __restrict__ wsf)
{
    if (blockIdx.x < 107) {
        int i = blockIdx.x * 256 + threadIdx.x;
        if (i < 8192) {                       // w1 [128][48] -> [128][64] pad
            int o = i >> 6, c = i & 63;
            wsb[i] = (c < 48) ? f2bf(w1g[o * 48 + c]) : (short)0;
        } else if (i < 24576) {               // w2 [128][128]
            wsb[i] = f2bf(w2g[i - 8192]);
        } else if (i < 26624) {               // w3 [12][128] -> [16][128] pad
            int k = i - 24576;
            wsb[i] = (k < 1536) ? f2bf(w3g[k]) : (short)0;
        } else if (i < 26672) {
            wsf[WSF_BP + (i - 26624)] = bpg[i - 26624];
        } else if (i < 26800) {
            wsf[WSF_B1 + (i - 26672)] = b1g[i - 26672];
        } else if (i < 26928) {
            wsf[WSF_B2 + (i - 26800)] = b2g[i - 26800];
        } else if (i < 27360) {
            wsf[WSF_WP + (i - 26928)] = wpg[i - 26928];
        }
        return;
    }
    int b = blockIdx.x - 107;
    int lane = threadIdx.x;
    if (lane >= 64) return;
    float tv = (float)t[b];
    float s0 = 0.f, s1 = 0.f, s2 = 0.f;
    const float LOG1E4 = 9.210340371976184f;
    #pragma unroll
    for (int ii = 0; ii < 2; ++ii) {
        int i = lane + ii * 64;
        float invf = __expf(-LOG1E4 * (float)i * (1.0f / 128.0f));
        float ang = tv * invf;
        float sn = sinf(ang), cs = cosf(ang);
        float ss = sn / (1.0f + __expf(-sn));
        float sc = cs / (1.0f + __expf(-cs));
        s0 += ss * wt[0 * 256 + i] + sc * wt[0 * 256 + i + 128];
        s1 += ss * wt[1 * 256 + i] + sc * wt[1 * 256 + i + 128];
        s2 += ss * wt[2 * 256 + i] + sc * wt[2 * 256 + i + 128];
    }
    #pragma unroll
    for (int off = 32; off; off >>= 1) {
        s0 += __shfl_down(s0, off);
        s1 += __shfl_down(s1, off);
        s2 += __shfl_down(s2, off);
    }
    if (lane == 0) {
        wsf[WSF_EMB + b * 3 + 0] = s0 + bt[0];
        wsf[WSF_EMB + b * 3 + 1] = s1 + bt[1];
        wsf[WSF_EMB + b * 3 + 2] = s2 + bt[2];
    }
}

// ---------------- main fused kernel ----------------
// MFMA 16x16x32 (m89): A lane(i=lane&15,q) holds A[i][q*8+j]; B symmetric:
// lane holds B[q*8+j][i]. D: col(N)=lane&15, row(M)=q*4+r.
__global__ __launch_bounds__(256, 3) void canet_main(
    const float* __restrict__ xg,   // (16,3,256,256)
    const float* __restrict__ hg,   // (16,9,256,256)
    const short* __restrict__ wsb,
    const float* __restrict__ wsf,
    float* __restrict__ outg)
{
    __shared__ __align__(16) short percS[64 * PERC_S];
    __shared__ __align__(16) short h1S[64 * ACT_S];
    __shared__ __align__(16) short h2S[64 * ACT_S];
    __shared__ __align__(16) float wp_s[592];   // skewed: oc*12 + 4*(oc/12) + k
    __shared__ float bp_s[48];

    const int tid = threadIdx.x;
    const int b = blockIdx.x >> 8;
    const int y = blockIdx.x & 255;

    for (int i = tid; i < 576; i += 256) {
        int oc = i / 12, k = i % 12;
        wp_s[i + (oc / 12) * 4] = (k < 9) ? wsf[WSF_WP + oc * 9 + k] : 0.0f;
    }
    if (tid < 48) bp_s[tid] = wsf[WSF_BP + tid];

    // zero percS K-pad (orig cols 48..63, swizzled) once; never written again
    {
        int r = tid >> 2, c = tid & 3;
        *(uint2*)(percS + r * PERC_S + ((48 + c * 4) ^ ((r & 7) << 3))) = uint2{0u, 0u};
    }

    const int wv = tid >> 6;
    const int lane = tid & 63;
    const int m = lane & 15;
    const int q = lane >> 4;
    const int rsw = (m & 7) << 3;   // swizzle: every row this lane touches is == m (mod 16)

    // ---- weight fragments to registers (once per block) ----
    bf16x8 w1f[2][2], w2f[2][4], w3f[4];
    #pragma unroll
    for (int j = 0; j < 2; ++j) {
        int n = wv * 32 + j * 16 + m;
        #pragma unroll
        for (int ks = 0; ks < 2; ++ks)
            w1f[j][ks] = *(const bf16x8*)(wsb + n * 64 + ks * 32 + q * 8);
        #pragma unroll
        for (int ks = 0; ks < 4; ++ks)
            w2f[j][ks] = *(const bf16x8*)(wsb + 8192 + n * 128 + ks * 32 + q * 8);
    }
    #pragma unroll
    for (int ks = 0; ks < 4; ++ks)
        w3f[ks] = *(const bf16x8*)(wsb + 24576 + m * 128 + ks * 32 + q * 8);

    // bias vectors: D rows = channels (wv*32 + j*16 + q*4 + r)
    f32x4 b1v[2], b2v[2];
    #pragma unroll
    for (int j = 0; j < 2; ++j) {
        b1v[j] = *(const f32x4*)(wsf + WSF_B1 + wv * 32 + j * 16 + q * 4);
        b2v[j] = *(const f32x4*)(wsf + WSF_B2 + wv * 32 + j * 16 + q * 4);
    }
    const float embv = (m < 3) ? wsf[WSF_EMB + b * 3 + m] : 0.0f;

    // conv source pointers (lane's 3 input channels: ic = 3q + i3)
    const float* src3[3];
    #pragma unroll
    for (int i3 = 0; i3 < 3; ++i3) {
        int ic = 3 * q + i3;
        src3[i3] = (ic < 3) ? (xg + (((size_t)b * 3 + ic) << 16))
                            : (hg + (((size_t)b * 9 + (ic - 3)) << 16));
    }

    __syncthreads();   // wp_s/bp_s/percS-pad ready

    for (int it = 0; it < 4; ++it) {
        const int x0 = it * 64;
        const int px = x0 + wv * 16 + m;

        // ---- depthwise 3x3 conv -> percS[px][ch] (swizzled cols) ----
        {
            const int xm1 = px - (px > 0);
            const int xp1 = px + (px < 255);
            const bool okl = (px > 0), okr = (px < 255);
            short* prow = percS + (wv * 16 + m) * PERC_S;
            const bool interior = (y >= 1) && (y <= 254);
            #pragma unroll
            for (int i3 = 0; i3 < 3; ++i3) {
                const float* s = src3[i3];
                float tap[9];
                if (interior) {
                    #pragma unroll
                    for (int ky = 0; ky < 3; ++ky) {
                        const float* rp = s + (y + ky - 1) * 256;
                        float c0 = rp[xm1], c1 = rp[px], c2 = rp[xp1];
                        tap[ky * 3 + 0] = okl ? c0 : 0.0f;
                        tap[ky * 3 + 1] = c1;
                        tap[ky * 3 + 2] = okr ? c2 : 0.0f;
                    }
                } else {
                    #pragma unroll
                    for (int ky = 0; ky < 3; ++ky) {
                        int yy = y + ky - 1;
                        bool yok = (yy >= 0) && (yy < 256);
                        const float* rp = s + (yok ? yy : y) * 256;
                        float c0 = rp[xm1], c1 = rp[px], c2 = rp[xp1];
                        tap[ky * 3 + 0] = (yok && okl) ? c0 : 0.0f;
                        tap[ky * 3 + 1] = yok ? c1 : 0.0f;
                        tap[ky * 3 + 2] = (yok && okr) ? c2 : 0.0f;
                    }
                }
                float v[4];
                #pragma unroll
                for (int r = 0; r < 4; ++r) {
                    int oc = 12 * q + 4 * i3 + r;
                    const float* wrow = &wp_s[oc * 12 + 4 * q];   // bank-skewed
                    f32x4 w0 = *(const f32x4*)wrow;
                    f32x4 w1_ = *(const f32x4*)(wrow + 4);
                    float a = bp_s[oc];
                    a += w0[0] * tap[0] + w0[1] * tap[1] + w0[2] * tap[2] + w0[3] * tap[3];
                    a += w1_[0] * tap[4] + w1_[1] * tap[5] + w1_[2] * tap[6] + w1_[3] * tap[7];
                    a += wrow[8] * tap[8];
                    v[r] = a;
                }
                uint2 pk;
                pk.x = pk2bf(v[0], v[1]);
                pk.y = pk2bf(v[2], v[3]);
                *(uint2*)(prow + ((12 * q + 4 * i3) ^ rsw)) = pk;
            }
            // K pad (orig cols 48..63) stays zero (written once pre-loop)
        }
        __syncthreads();

        // ---- GEMM1 (swapped): D[ch][px] = w1 . perc^T ; write h1S[px][ch] ----
        #pragma unroll
        for (int nt = 0; nt < 4; ++nt) {
            f32x4 c0 = b1v[0], c1 = b1v[1];
            #pragma unroll
            for (int ks = 0; ks < 2; ++ks) {
                bf16x8 p = *(const bf16x8*)(percS + (nt * 16 + m) * PERC_S + ((ks * 32 + q * 8) ^ rsw));
                c0 = __builtin_amdgcn_mfma_f32_16x16x32_bf16(w1f[0][ks], p, c0, 0, 0, 0);
                c1 = __builtin_amdgcn_mfma_f32_16x16x32_bf16(w1f[1][ks], p, c1, 0, 0, 0);
            }
            short* drow = h1S + (nt * 16 + m) * ACT_S;
            uint2 pk;
            pk.x = pk2bf(fmaxf(c0[0], 0.f), fmaxf(c0[1], 0.f));
            pk.y = pk2bf(fmaxf(c0[2], 0.f), fmaxf(c0[3], 0.f));
            *(uint2*)(drow + ((wv * 32 + q * 4) ^ rsw)) = pk;
            pk.x = pk2bf(fmaxf(c1[0], 0.f), fmaxf(c1[1], 0.f));
            pk.y = pk2bf(fmaxf(c1[2], 0.f), fmaxf(c1[3], 0.f));
            *(uint2*)(drow + ((wv * 32 + q * 4 + 16) ^ rsw)) = pk;
        }
        __syncthreads();

        // ---- GEMM2 (swapped): D[ch][px] = w2 . h1^T ; write h2S[px][ch] ----
        #pragma unroll
        for (int nt = 0; nt < 4; ++nt) {
            f32x4 c0 = b2v[0], c1 = b2v[1];
            #pragma unroll
            for (int ks = 0; ks < 4; ++ks) {
                bf16x8 a = *(const bf16x8*)(h1S + (nt * 16 + m) * ACT_S + ((ks * 32 + q * 8) ^ rsw));
                c0 = __builtin_amdgcn_mfma_f32_16x16x32_bf16(w2f[0][ks], a, c0, 0, 0, 0);
                c1 = __builtin_amdgcn_mfma_f32_16x16x32_bf16(w2f[1][ks], a, c1, 0, 0, 0);
            }
            short* drow = h2S + (nt * 16 + m) * ACT_S;
            uint2 pk;
            pk.x = pk2bf(fmaxf(c0[0], 0.f), fmaxf(c0[1], 0.f));
            pk.y = pk2bf(fmaxf(c0[2], 0.f), fmaxf(c0[3], 0.f));
            *(uint2*)(drow + ((wv * 32 + q * 4) ^ rsw)) = pk;
            pk.x = pk2bf(fmaxf(c1[0], 0.f), fmaxf(c1[1], 0.f));
            pk.y = pk2bf(fmaxf(c1[2], 0.f), fmaxf(c1[3], 0.f));
            *(uint2*)(drow + ((wv * 32 + q * 4 + 16) ^ rsw)) = pk;
        }
        __syncthreads();

        // ---- GEMM3: out = h2 . w3^T ; D col=oc, row=px; float4 store ----
        {
            f32x4 acc = {0.f, 0.f, 0.f, 0.f};
            #pragma unroll
            for (int ks = 0; ks < 4; ++ks) {
                bf16x8 a = *(const bf16x8*)(h2S + (wv * 16 + m) * ACT_S + ((ks * 32 + q * 8) ^ rsw));
                acc = __builtin_amdgcn_mfma_f32_16x16x32_bf16(a, w3f[ks], acc, 0, 0, 0);
            }
            if (m < 12) {
                int xx0 = x0 + wv * 16 + q * 4;
                size_t idx;
                if (m < 3) {
                    idx = (size_t)NOISE_BASE + (((size_t)b * 3 + m) << 16) + (size_t)y * 256 + xx0;
                } else {
                    idx = (((size_t)b * 9 + (m - 3)) << 16) + (size_t)y * 256 + xx0;
                }
                f32x4 vst = {acc[0] + embv, acc[1] + embv, acc[2] + embv, acc[3] + embv};
                *(f32x4*)(outg + idx) = vst;
            }
        }
        // next-iter conv writes percS only after this iter's GEMM1 barrier.
    }
}

extern "C" void kernel_launch(void* const* d_in, const int* in_sizes, int n_in,
                              void* d_out, int out_size, void* d_ws, size_t ws_size,
                              hipStream_t stream) {
    const float* xg  = (const float*)d_in[0];
    const float* hg  = (const float*)d_in[1];
    const int*   tg  = (const int*)  d_in[2];
    const float* wpg = (const float*)d_in[3];
    const float* bpg = (const float*)d_in[4];
    const float* w1g = (const float*)d_in[5];
    const float* b1g = (const float*)d_in[6];
    const float* w2g = (const float*)d_in[7];
    const float* b2g = (const float*)d_in[8];
    const float* w3g = (const float*)d_in[9];
    const float* wtg = (const float*)d_in[10];
    const float* btg = (const float*)d_in[11];
    float* outg = (float*)d_out;
    short* wsb  = (short*)d_ws;
    float* wsf  = (float*)d_ws + WSF_OFF;

    prep_emb_kernel<<<123, 256, 0, stream>>>(wpg, bpg, w1g, b1g, w2g, b2g, w3g,
                                             tg, wtg, btg, wsb, wsf);
    canet_main<<<4096, 256, 0, stream>>>(xg, hg, wsb, wsf, outg);
}